// Round 8
// baseline (299.527 us; speedup 1.0000x reference)
//
#include <hip/hip_runtime.h>

#define HH 512
#define WW 512
#define NPIX (HH*WW)      // 2^18
#define BATCH 16
#define NIMG 32           // 16 ref + 16 tgt

typedef unsigned char uchar;
typedef unsigned long long u64;

// ---------------- Stage 1: luminance (float4 vectorized) ----------
__global__ __launch_bounds__(256) void k_lum(const float4* __restrict__ ref,
                                             const float4* __restrict__ tgt,
                                             float4* __restrict__ lum) {
    int idx = blockIdx.x * 256 + threadIdx.x;     // NIMG * NPIX/4 threads
    int img = idx >> 16;                          // NPIX/4 = 65536
    int p4 = idx & 65535;
    const float4* src = (img < BATCH) ? (ref + (size_t)img * 3 * 65536)
                                      : (tgt + (size_t)(img - BATCH) * 3 * 65536);
    float4 r = src[p4];
    float4 g = src[65536 + p4];
    float4 b = src[131072 + p4];
    float4 o;
    o.x = 0.299f * r.x + 0.587f * g.x + 0.114f * b.x;
    o.y = 0.299f * r.y + 0.587f * g.y + 0.114f * b.y;
    o.z = 0.299f * r.z + 0.587f * g.z + 0.114f * b.z;
    o.w = 0.299f * r.w + 0.587f * g.w + 0.114f * b.w;
    lum[idx] = o;
}

// ---- Stage 2+3+4 fused: sobel -> E bits -> dilate -> M bits -> variance ----
// Tile 32x32. lum halo 44x44 in LDS (stride 45, odd). E rows: 42 u64 bitmasks
// (bit b = col x0-5+b) via __ballot. Dilation: row-OR + bit-shift-OR. M rows:
// p = prox, v = bg as u64 bitmasks (bits 2..39 used). H-sum planes stride 33.
#define LSTR 45            // lum tile stride (odd)
#define HSTR 33            // plane stride (odd)

__inline__ __device__ float wave_reduce(float v) {
#pragma unroll
    for (int o = 32; o > 0; o >>= 1) v += __shfl_down(v, o);
    return v;
}

__global__ __launch_bounds__(256, 4) void k_sdv(const float* __restrict__ lum,
                                                unsigned* __restrict__ Mg,
                                                double* __restrict__ acc) {
    __shared__ float Ls[44 * LSTR];        // 7920 B
    __shared__ u64 Erow[42];               // 336 B
    __shared__ u64 Mp[38], Mv[38];         // 608 B
    __shared__ unsigned Pcnt[38 * HSTR];   // 5016 B each x5 = 25080 B
    __shared__ float Ps1[38 * HSTR];
    __shared__ float Ps2[38 * HSTR];
    __shared__ float Vs1[38 * HSTR];
    __shared__ float Vs2[38 * HSTR];
    __shared__ float red[4][4];

    int bi = blockIdx.x;
    int img = bi >> 8;
    int t = bi & 255;
    int y0 = (t >> 4) << 5;
    int x0 = (t & 15) << 5;
    const float* L = lum + (size_t)img * NPIX;
    int tid = threadIdx.x;
    int lane = tid & 63;
    int wid = tid >> 6;

    // ---- load lum halo 44x44 (zero-padded) ----
    for (int i = tid; i < 44 * 44; i += 256) {
        int r = i / 44, c = i - r * 44;
        int gy = y0 - 6 + r, gx = x0 - 6 + c;
        Ls[r * LSTR + c] = ((unsigned)gy < HH && (unsigned)gx < WW) ? L[gy * WW + gx] : 0.0f;
    }
    __syncthreads();

    // ---- E rows via ballot: 42 rows (global y0-5+rE), bit b = col x0-5+b ----
    for (int rE = wid; rE < 42; rE += 4) {
        int b = lane;
        int bc = (b < 42) ? b : 41;
        int base = (rE + 1) * LSTR + (bc + 1);
        float v00 = Ls[base - LSTR - 1], v01 = Ls[base - LSTR], v02 = Ls[base - LSTR + 1];
        float v10 = Ls[base - 1],                                v12 = Ls[base + 1];
        float v20 = Ls[base + LSTR - 1], v21 = Ls[base + LSTR], v22 = Ls[base + LSTR + 1];
        float gxv = (v02 - v00) + 2.0f * (v12 - v10) + (v22 - v20);
        float gyv = (v20 - v00) + 2.0f * (v21 - v01) + (v22 - v02);
        float grad = sqrtf(gxv * gxv + gyv * gyv + 1e-12f);
        u64 bits = __ballot((b < 42) && (grad > 0.1f));
        if (lane == 0) Erow[rE] = bits;
    }
    __syncthreads();

    // ---- dilation + M bitmask rows (38 rows, global y0-3+t) ----
    if (tid < 38) {
        int gy = y0 - 3 + tid;
        u64 o = Erow[tid] | Erow[tid + 1] | Erow[tid + 2] | Erow[tid + 3] | Erow[tid + 4];
        u64 h = o | (o << 1) | (o << 2) | (o >> 1) | (o >> 2);
        u64 e = Erow[tid + 2];
        int lowb = 5 - x0; if (lowb < 2) lowb = 2;
        int highb = 516 - x0; if (highb > 39) highb = 39;
        u64 vm = ((~0ull) << lowb) & ((~0ull) >> (63 - highb));
        u64 p = 0, v = 0;
        if ((unsigned)gy < HH) { p = h & ~e & vm; v = (~h) & vm; }
        Mp[tid] = p; Mv[tid] = v;
        if (tid >= 3 && tid < 35) {   // output rows: write packed prox word (32 cols)
            unsigned w32 = (unsigned)(p >> 5);
            Mg[(size_t)img * (HH * 16) + (size_t)gy * 16 + (x0 >> 5)] = w32;
        }
    }
    __syncthreads();

    // ---- phase 1: horizontal sliding 7-sums: 38 rows x 8 segments of 4 ----
    for (int i = tid; i < 38 * 8; i += 256) {
        int r = i >> 3, s = i & 7;
        int cc0 = s << 2;
        unsigned mp32 = (unsigned)(Mp[r] >> (cc0 + 2));
        unsigned mv32 = (unsigned)(Mv[r] >> (cc0 + 2));
        const float* lr = &Ls[(r + 3) * LSTR + (cc0 + 3)];
        float lv[10];
#pragma unroll
        for (int dx = 0; dx < 10; ++dx) lv[dx] = lr[dx];

        int cp = 0, cv = 0;
        float s1p = 0, s2p = 0, s1v = 0, s2v = 0;
#pragma unroll
        for (int dx = 0; dx < 7; ++dx) {
            float l = lv[dx];
            int p = (mp32 >> dx) & 1, v = (mv32 >> dx) & 1;
            float pf = (float)p, vf = (float)v;
            float pl = pf * l, vl = vf * l;
            cp += p; cv += v;
            s1p += pl; s2p = fmaf(pl, l, s2p);
            s1v += vl; s2v = fmaf(vl, l, s2v);
        }
        int itm = r * HSTR + cc0;
        Pcnt[itm] = (unsigned)cp | ((unsigned)cv << 8);
        Ps1[itm] = s1p; Ps2[itm] = s2p; Vs1[itm] = s1v; Vs2[itm] = s2v;
#pragma unroll
        for (int c = 1; c < 4; ++c) {
            {   // add tap c+6
                float l = lv[c + 6];
                int p = (mp32 >> (c + 6)) & 1, v = (mv32 >> (c + 6)) & 1;
                float pf = (float)p, vf = (float)v;
                float pl = pf * l, vl = vf * l;
                cp += p; cv += v;
                s1p += pl; s2p = fmaf(pl, l, s2p);
                s1v += vl; s2v = fmaf(vl, l, s2v);
            }
            {   // sub tap c-1
                float l = lv[c - 1];
                int p = (mp32 >> (c - 1)) & 1, v = (mv32 >> (c - 1)) & 1;
                float pf = (float)p, vf = (float)v;
                float pl = pf * l, vl = vf * l;
                cp -= p; cv -= v;
                s1p -= pl; s2p = fmaf(-pl, l, s2p);
                s1v -= vl; s2v = fmaf(-vl, l, s2v);
            }
            Pcnt[itm + c] = (unsigned)cp | ((unsigned)cv << 8);
            Ps1[itm + c] = s1p; Ps2[itm + c] = s2p; Vs1[itm + c] = s1v; Vs2[itm + c] = s2v;
        }
    }
    __syncthreads();

    // ---- phase 2: vertical sliding 7-sums + variance ----
    int x = tid & 31;
    int ybase = (tid >> 5) << 2;   // 8 groups of 4 consecutive output rows
    unsigned pc = 0;
    float s1p = 0, s2p = 0, s1v = 0, s2v = 0;
    float c0a = 0, c1a = 0, c2a = 0, c3a = 0;

#pragma unroll
    for (int dy = 0; dy < 7; ++dy) {
        int it = (ybase + dy) * HSTR + x;
        pc += Pcnt[it]; s1p += Ps1[it]; s2p += Ps2[it]; s1v += Vs1[it]; s2v += Vs2[it];
    }
#pragma unroll
    for (int k = 0; k < 4; ++k) {
        if (k > 0) {
            int ita = (ybase + k + 6) * HSTR + x;
            int its = (ybase + k - 1) * HSTR + x;
            pc += Pcnt[ita] - Pcnt[its];
            s1p += Ps1[ita] - Ps1[its];
            s2p += Ps2[ita] - Ps2[its];
            s1v += Vs1[ita] - Vs1[its];
            s2v += Vs2[ita] - Vs2[its];
        }
        int mrow = ybase + k + 3;
        float mp0 = (float)((Mp[mrow] >> (x + 5)) & 1ull);
        float mb0 = (float)((Mv[mrow] >> (x + 5)) & 1ull);
        float cpf = (float)(pc & 0xffu);
        float cvf = (float)(pc >> 8);
        float Cp = fmaxf(cpf, 1.0f);
        float meanp = s1p / Cp;
        float varp = fmaxf(s2p / Cp - meanp * meanp, 0.0f);
        float Cb = fmaxf(cvf, 1.0f);
        float meanb = s1v / Cb;
        float varb = fmaxf(s2v / Cb - meanb * meanb, 0.0f);
        c0a += varp * mp0; c1a += mp0;
        c2a += varb * mb0; c3a += mb0;
    }

    c0a = wave_reduce(c0a); c1a = wave_reduce(c1a);
    c2a = wave_reduce(c2a); c3a = wave_reduce(c3a);
    if (lane == 0) { red[wid][0] = c0a; red[wid][1] = c1a; red[wid][2] = c2a; red[wid][3] = c3a; }
    __syncthreads();
    if (tid == 0) {
        double t0 = 0, t1 = 0, t2 = 0, t3 = 0;
        for (int w = 0; w < 4; ++w) { t0 += red[w][0]; t1 += red[w][1]; t2 += red[w][2]; t3 += red[w][3]; }
        atomicAdd(&acc[img * 4 + 0], t0);
        atomicAdd(&acc[img * 4 + 1], t1);
        atomicAdd(&acc[img * 4 + 2], t2);
        atomicAdd(&acc[img * 4 + 3], t3);
    }
}

// ---------------- Stage 5a: per-image ringing flags ----------------
__global__ void k_flags(const double* __restrict__ acc, float* __restrict__ flags) {
    int i = threadIdx.x;
    if (i >= NIMG) return;
    const double* a = acc + (size_t)i * 4;
    double vp = a[0] / fmax(a[1], 1.0);
    double vb = a[2] / fmax(a[3], 1.0);
    flags[i] = ((vp / (vb + 1e-12)) > 2.0) ? 1.0f : 0.0f;
}

// ---------------- Stage 5b: output from bit-packed prox masks ----------------
__global__ __launch_bounds__(256) void k_out(const unsigned* __restrict__ Mg,
                                             const float* __restrict__ flags,
                                             float4* __restrict__ out) {
    int idx = blockIdx.x * 256 + threadIdx.x;   // BATCH * NPIX/4 threads
    int b = idx >> 16;
    int p4 = idx & 65535;                        // group of 4 px
    int row = p4 >> 7;                           // 128 groups per row
    int xg = p4 & 127;
    int wi = xg >> 3;                            // word index (32 px per word)
    int sh = (xg & 7) << 2;                      // bit shift of this 4-px group
    float fr = flags[b], ft = flags[b + BATCH];
    unsigned wr = Mg[(size_t)b * (HH * 16) + (size_t)row * 16 + wi];
    unsigned wt = Mg[(size_t)(b + BATCH) * (HH * 16) + (size_t)row * 16 + wi];
    unsigned r4 = (wr >> sh) & 0xF;
    unsigned t4 = (wt >> sh) & 0xF;
    float4 o;
    o.x = fmaxf(((t4 & 1) ? ft : 0.0f) - ((r4 & 1) ? fr : 0.0f), 0.0f);
    o.y = fmaxf(((t4 & 2) ? ft : 0.0f) - ((r4 & 2) ? fr : 0.0f), 0.0f);
    o.z = fmaxf(((t4 & 4) ? ft : 0.0f) - ((r4 & 4) ? fr : 0.0f), 0.0f);
    o.w = fmaxf(((t4 & 8) ? ft : 0.0f) - ((r4 & 8) ? fr : 0.0f), 0.0f);
    out[idx] = o;
}

extern "C" void kernel_launch(void* const* d_in, const int* in_sizes, int n_in,
                              void* d_out, int out_size, void* d_ws, size_t ws_size,
                              hipStream_t stream) {
    const float* ref = (const float*)d_in[0];
    const float* tgt = (const float*)d_in[1];
    float* out = (float*)d_out;

    char* ws = (char*)d_ws;
    double* acc = (double*)ws;                       // 32*4 doubles = 1 KB
    float* flags = (float*)(ws + 1024);              // 32 floats
    float* lum = (float*)(ws + 2048);                // 32 MB
    unsigned* Mg = (unsigned*)(ws + 2048 + (size_t)NIMG * NPIX * 4);  // 1 MB packed prox bits

    (void)hipMemsetAsync(acc, 0, NIMG * 4 * sizeof(double), stream);

    int nAll = NIMG * NPIX;          // 8388608
    k_lum<<<nAll / 4 / 256, 256, 0, stream>>>((const float4*)ref, (const float4*)tgt, (float4*)lum);
    k_sdv<<<NIMG * 256, 256, 0, stream>>>(lum, Mg, acc);
    k_flags<<<1, 64, 0, stream>>>(acc, flags);
    k_out<<<BATCH * NPIX / 4 / 256, 256, 0, stream>>>(Mg, flags, (float4*)out);
}

// Round 9
// 243.351 us; speedup vs baseline: 1.2308x; 1.2308x over previous
//
#include <hip/hip_runtime.h>

#define HH 512
#define WW 512
#define NPIX (HH*WW)      // 2^18
#define BATCH 16
#define NIMG 32           // 16 ref + 16 tgt

typedef unsigned char uchar;
typedef unsigned long long u64;

// ---------------- Stage 1: luminance (float4 vectorized) ----------
__global__ __launch_bounds__(256) void k_lum(const float4* __restrict__ ref,
                                             const float4* __restrict__ tgt,
                                             float4* __restrict__ lum) {
    int idx = blockIdx.x * 256 + threadIdx.x;     // NIMG * NPIX/4 threads
    int img = idx >> 16;                          // NPIX/4 = 65536
    int p4 = idx & 65535;
    const float4* src = (img < BATCH) ? (ref + (size_t)img * 3 * 65536)
                                      : (tgt + (size_t)(img - BATCH) * 3 * 65536);
    float4 r = src[p4];
    float4 g = src[65536 + p4];
    float4 b = src[131072 + p4];
    float4 o;
    o.x = 0.299f * r.x + 0.587f * g.x + 0.114f * b.x;
    o.y = 0.299f * r.y + 0.587f * g.y + 0.114f * b.y;
    o.z = 0.299f * r.z + 0.587f * g.z + 0.114f * b.z;
    o.w = 0.299f * r.w + 0.587f * g.w + 0.114f * b.w;
    lum[idx] = o;
}

// ---- Stages 2+3+4: barrier-free wave-pipelined strip kernel ----
// One wave = 52 output cols x 32 output rows. Rolling register pipeline over
// rows: lum triples (3+1 rows), E/hE/p/v as ballot bitmasks, 7-deep moment
// ring for the vertical sliding window. No LDS, no __syncthreads.
// Lane -> col = sx*52 + lane - 6; outputs from lanes 6..57.

#define SHLF(v,d) __shfl((v), ((lane - (d)) < 0 ? 0 : (lane - (d))))
#define SHRF(v,d) __shfl((v), ((lane + (d)) > 63 ? 63 : (lane + (d))))

__inline__ __device__ float wave_reduce(float v) {
#pragma unroll
    for (int o = 32; o > 0; o >>= 1) v += __shfl_down(v, o);
    return v;
}

__global__ __launch_bounds__(256, 4) void k_strip(const float* __restrict__ lum,
                                                  uchar* __restrict__ Mo_g,
                                                  double* __restrict__ acc) {
    int lane = threadIdx.x & 63;
    int gw = blockIdx.x * 4 + (threadIdx.x >> 6);   // 0..5119
    int img = gw / 160;                             // 10 sx * 16 sy
    int rem = gw - img * 160;
    int sy = rem / 10;
    int sx = rem - sy * 10;
    int r0 = sy << 5;          // first output row
    int c0 = sx * 52;
    int col = c0 + lane - 6;
    bool colok = (unsigned)col < WW;

    const float* Lp = lum + (size_t)img * NPIX;
    uchar* Mo = Mo_g + (size_t)img * NPIX;

    // rolling lum triples: rows (slot0=oldest=L-3 .. slot3=L)
    float tm0 = 0, tm1 = 0, tm2 = 0, tm3 = 0;
    float tc0 = 0, tc1 = 0, tc2 = 0, tc3 = 0;
    float tp0 = 0, tp1 = 0, tp2 = 0, tp3 = 0;
    unsigned eb = 0, hb = 0, pbm = 0, vbm = 0;

#define LOADROW(Lr) { \
    tm0 = tm1; tc0 = tc1; tp0 = tp1; \
    tm1 = tm2; tc1 = tc2; tp1 = tp2; \
    tm2 = tm3; tc2 = tc3; tp2 = tp3; \
    float ln = 0.0f; \
    if (((unsigned)(Lr) < HH) && colok) ln = Lp[(size_t)(Lr) * WW + col]; \
    tc3 = ln; tm3 = SHLF(ln, 1); tp3 = SHRF(ln, 1); }

#define SOBEL_E(Lr) { \
    float gx = (tp1 - tm1) + 2.0f * (tp2 - tm2) + (tp3 - tm3); \
    float gy = (tm3 + 2.0f * tc3 + tp3) - (tm1 + 2.0f * tc1 + tp1); \
    float grad = sqrtf(gx * gx + gy * gy + 1e-12f); \
    bool e = (grad > 0.1f) && colok && ((unsigned)((Lr) - 1) < HH); \
    u64 ebal = __ballot(e); \
    eb = (eb << 1) | (e ? 1u : 0u); \
    unsigned hE5 = (unsigned)((ebal << 2) >> lane) & 0x1Fu; \
    hb = (hb << 1) | (hE5 ? 1u : 0u); }

    // ---- pre-roll: rows r0-6, r0-5 ----
    for (int q = 0; q < 2; ++q) { int Lr = r0 - 6 + q; LOADROW(Lr); }
    // ---- warm: rows r0-4..r0-1 (E/hE only) ----
    for (int q = 0; q < 4; ++q) { int Lr = r0 - 4 + q; LOADROW(Lr); SOBEL_E(Lr); }

    // ---- steady: 42 iterations, ring unrolled x7 ----
    float r1p[7], r2p[7], r1v[7], r2v[7];
    unsigned rcn[7];
    unsigned cnt_acc = 0;
    float a1p = 0, a2p = 0, a1v = 0, a2v = 0;
    float c0a = 0, c1a = 0, c2a = 0, c3a = 0;

    for (int o6 = 0; o6 < 6; ++o6) {
#pragma unroll
        for (int u = 0; u < 7; ++u) {
            int j = o6 * 7 + u;
            int Lr = r0 + j;
            LOADROW(Lr);
            SOBEL_E(Lr);
            int m = Lr - 3;
            bool ed = (hb & 0x1Fu) != 0;
            bool e3 = ((eb >> 2) & 1u) != 0;
            bool mrowok = (unsigned)m < HH;
            bool pp = ed && !e3 && mrowok && colok;
            bool vv = (!ed) && mrowok && colok;
            u64 pb = __ballot(pp);
            u64 vb = __ballot(vv);
            pbm = (pbm << 1) | (pp ? 1u : 0u);
            vbm = (vbm << 1) | (vv ? 1u : 0u);

            float xx0 = SHLF(tm0, 2);   // col-3
            float xx1 = SHLF(tc0, 2);   // col-2
            float xx2 = tm0;            // col-1
            float xx3 = tc0;            // col
            float xx4 = tp0;            // col+1
            float xx5 = SHRF(tc0, 2);   // col+2
            float xx6 = SHRF(tp0, 2);   // col+3
            unsigned pw = (unsigned)((pb << 3) >> lane) & 0x7Fu;
            unsigned vw = (unsigned)((vb << 3) >> lane) & 0x7Fu;
            unsigned cnt_new = (unsigned)__popc(pw) | ((unsigned)__popc(vw) << 8);
            float s1p = 0, s2p = 0, s1v = 0, s2v = 0;
#define TAP(i, xi) { float xq = (xi) * (xi); \
            s1p += ((pw >> (i)) & 1u) ? (xi) : 0.0f; \
            s2p += ((pw >> (i)) & 1u) ? xq : 0.0f; \
            s1v += ((vw >> (i)) & 1u) ? (xi) : 0.0f; \
            s2v += ((vw >> (i)) & 1u) ? xq : 0.0f; }
            TAP(0, xx0) TAP(1, xx1) TAP(2, xx2) TAP(3, xx3)
            TAP(4, xx4) TAP(5, xx5) TAP(6, xx6)
#undef TAP

            if (j >= 7) {   // slide out row m-7
                cnt_acc -= rcn[u];
                a1p -= r1p[u]; a2p -= r2p[u]; a1v -= r1v[u]; a2v -= r2v[u];
            }
            cnt_acc += cnt_new;
            a1p += s1p; a2p += s2p; a1v += s1v; a2v += s2v;
            rcn[u] = cnt_new; r1p[u] = s1p; r2p[u] = s2p; r1v[u] = s1v; r2v[u] = s2v;

            if (j >= 3 && j <= 34) {   // write prox byte for owned row m
                if (lane >= 6 && lane <= 57 && colok)
                    Mo[(size_t)m * WW + col] = (uchar)(pp ? 1 : 0);
            }
            if (j >= 6 && j <= 37) {   // output row y = Lr-6
                float mp0 = (float)((pbm >> 3) & 1u);
                float mb0 = (float)((vbm >> 3) & 1u);
                if (lane < 6 || lane > 57) { mp0 = 0.0f; mb0 = 0.0f; }
                float cpf = (float)(cnt_acc & 0xFFu);
                float cvf = (float)((cnt_acc >> 8) & 0xFFu);
                float Cp = fmaxf(cpf, 1.0f);
                float meanp = a1p / Cp;
                float varp = fmaxf(a2p / Cp - meanp * meanp, 0.0f);
                float Cb = fmaxf(cvf, 1.0f);
                float meanb = a1v / Cb;
                float varb = fmaxf(a2v / Cb - meanb * meanb, 0.0f);
                c0a += varp * mp0; c1a += mp0;
                c2a += varb * mb0; c3a += mb0;
            }
        }
    }

    c0a = wave_reduce(c0a); c1a = wave_reduce(c1a);
    c2a = wave_reduce(c2a); c3a = wave_reduce(c3a);
    if (lane == 0) {
        atomicAdd(&acc[img * 4 + 0], (double)c0a);
        atomicAdd(&acc[img * 4 + 1], (double)c1a);
        atomicAdd(&acc[img * 4 + 2], (double)c2a);
        atomicAdd(&acc[img * 4 + 3], (double)c3a);
    }
}

// ---------------- Stage 5a: per-image ringing flags ----------------
__global__ void k_flags(const double* __restrict__ acc, float* __restrict__ flags) {
    int i = threadIdx.x;
    if (i >= NIMG) return;
    const double* a = acc + (size_t)i * 4;
    double vp = a[0] / fmax(a[1], 1.0);
    double vb = a[2] / fmax(a[3], 1.0);
    flags[i] = ((vp / (vb + 1e-12)) > 2.0) ? 1.0f : 0.0f;
}

// ---------------- Stage 5b: output from prox byte masks ----------------
__global__ __launch_bounds__(256) void k_out(const uchar4* __restrict__ M,
                                             const float* __restrict__ flags,
                                             float4* __restrict__ out) {
    int idx = blockIdx.x * 256 + threadIdx.x;   // BATCH * NPIX/4 threads
    int b = idx >> 16;
    int p = idx & 65535;
    float fr = flags[b], ft = flags[b + BATCH];
    uchar4 mr = M[(size_t)b * 65536 + p];
    uchar4 mt = M[(size_t)(b + BATCH) * 65536 + p];
    float4 o;
    o.x = fmaxf((mt.x ? ft : 0.0f) - (mr.x ? fr : 0.0f), 0.0f);
    o.y = fmaxf((mt.y ? ft : 0.0f) - (mr.y ? fr : 0.0f), 0.0f);
    o.z = fmaxf((mt.z ? ft : 0.0f) - (mr.z ? fr : 0.0f), 0.0f);
    o.w = fmaxf((mt.w ? ft : 0.0f) - (mr.w ? fr : 0.0f), 0.0f);
    out[idx] = o;
}

extern "C" void kernel_launch(void* const* d_in, const int* in_sizes, int n_in,
                              void* d_out, int out_size, void* d_ws, size_t ws_size,
                              hipStream_t stream) {
    const float* ref = (const float*)d_in[0];
    const float* tgt = (const float*)d_in[1];
    float* out = (float*)d_out;

    char* ws = (char*)d_ws;
    double* acc = (double*)ws;                       // 32*4 doubles = 1 KB
    float* flags = (float*)(ws + 1024);              // 32 floats
    float* lum = (float*)(ws + 2048);                // 32 MB
    uchar* Mo = (uchar*)(ws + 2048 + (size_t)NIMG * NPIX * 4);  // 8 MB prox bytes

    (void)hipMemsetAsync(acc, 0, NIMG * 4 * sizeof(double), stream);

    int nAll = NIMG * NPIX;          // 8388608
    k_lum<<<nAll / 4 / 256, 256, 0, stream>>>((const float4*)ref, (const float4*)tgt, (float4*)lum);
    k_strip<<<1280, 256, 0, stream>>>(lum, Mo, acc);   // 5120 waves
    k_flags<<<1, 64, 0, stream>>>(acc, flags);
    k_out<<<BATCH * NPIX / 4 / 256, 256, 0, stream>>>((const uchar4*)Mo, flags, (float4*)out);
}

// Round 10
// 223.587 us; speedup vs baseline: 1.3396x; 1.0884x over previous
//
#include <hip/hip_runtime.h>

#define HH 512
#define WW 512
#define NPIX (HH*WW)      // 2^18
#define BATCH 16
#define NIMG 32           // 16 ref + 16 tgt

typedef unsigned char uchar;
typedef unsigned long long u64;

// ---------------- Stage 1: luminance (float4 vectorized) ----------
__global__ __launch_bounds__(256) void k_lum(const float4* __restrict__ ref,
                                             const float4* __restrict__ tgt,
                                             float4* __restrict__ lum) {
    int idx = blockIdx.x * 256 + threadIdx.x;     // NIMG * NPIX/4 threads
    int img = idx >> 16;                          // NPIX/4 = 65536
    int p4 = idx & 65535;
    const float4* src = (img < BATCH) ? (ref + (size_t)img * 3 * 65536)
                                      : (tgt + (size_t)(img - BATCH) * 3 * 65536);
    float4 r = src[p4];
    float4 g = src[65536 + p4];
    float4 b = src[131072 + p4];
    float4 o;
    o.x = 0.299f * r.x + 0.587f * g.x + 0.114f * b.x;
    o.y = 0.299f * r.y + 0.587f * g.y + 0.114f * b.y;
    o.z = 0.299f * r.z + 0.587f * g.z + 0.114f * b.z;
    o.w = 0.299f * r.w + 0.587f * g.w + 0.114f * b.w;
    lum[idx] = o;
}

// ---- Stages 2+3+4: barrier-free wave-pipelined strip kernel ----
// One wave = 52 output cols x 32 output rows. Rolling register pipeline over
// rows with an explicit 2-row global-load prefetch (preA/preB). E/hE/p/v as
// ballot bitmasks; 7-deep moment ring for the vertical sliding window.
// No LDS, no __syncthreads. Lane -> col = sx*52 + lane - 6; outputs lanes 6..57.

__inline__ __device__ float wave_reduce(float v) {
#pragma unroll
    for (int o = 32; o > 0; o >>= 1) v += __shfl_down(v, o);
    return v;
}

__global__ __launch_bounds__(256) void k_strip(const float* __restrict__ lum,
                                               uchar* __restrict__ Mo_g,
                                               double* __restrict__ acc) {
    int lane = threadIdx.x & 63;
    int gw = blockIdx.x * 4 + (threadIdx.x >> 6);   // 0..5119
    int img = gw / 160;                             // 10 sx * 16 sy
    int rem = gw - img * 160;
    int sy = rem / 10;
    int sx = rem - sy * 10;
    int r0 = sy << 5;          // first output row
    int c0 = sx * 52;
    int col = c0 + lane - 6;
    bool colok = (unsigned)col < WW;

    // precomputed clamped shuffle source lanes
    int lm1 = (lane > 0) ? lane - 1 : 0;
    int lp1 = (lane < 63) ? lane + 1 : 63;
    int lm2 = (lane > 1) ? lane - 2 : 0;
    int lp2 = (lane < 62) ? lane + 2 : 63;

    const float* Lp = lum + (size_t)img * NPIX;
    uchar* Mo = Mo_g + (size_t)img * NPIX;

    // rolling lum triples: slot0=oldest(L-3) .. slot3=newest(L)
    float tm0 = 0, tm1 = 0, tm2 = 0, tm3 = 0;
    float tc0 = 0, tc1 = 0, tc2 = 0, tc3 = 0;
    float tp0 = 0, tp1 = 0, tp2 = 0, tp3 = 0;
    unsigned eb = 0, hb = 0, pbm = 0, vbm = 0;

    // ---- explicit prefetch pipeline (depth 2) ----
    float preA = (((unsigned)(r0 - 6) < HH) && colok) ? Lp[(size_t)(r0 - 6) * WW + col] : 0.0f;
    float preB = (((unsigned)(r0 - 5) < HH) && colok) ? Lp[(size_t)(r0 - 5) * WW + col] : 0.0f;

#define LOADROW(Lr) { \
    tm0 = tm1; tc0 = tc1; tp0 = tp1; \
    tm1 = tm2; tc1 = tc2; tp1 = tp2; \
    tm2 = tm3; tc2 = tc3; tp2 = tp3; \
    float ln = preA; preA = preB; \
    { int rr = (Lr) + 2; \
      preB = (((unsigned)rr < HH) && colok) ? Lp[(size_t)rr * WW + col] : 0.0f; } \
    tc3 = ln; tm3 = __shfl(ln, lm1); tp3 = __shfl(ln, lp1); }

#define SOBEL_E(Lr) { \
    float gx = (tp1 - tm1) + 2.0f * (tp2 - tm2) + (tp3 - tm3); \
    float gy = (tm3 + 2.0f * tc3 + tp3) - (tm1 + 2.0f * tc1 + tp1); \
    float grad = sqrtf(gx * gx + gy * gy + 1e-12f); \
    bool e = (grad > 0.1f) && colok && ((unsigned)((Lr) - 1) < HH); \
    u64 ebal = __ballot(e); \
    eb = (eb << 1) | (e ? 1u : 0u); \
    unsigned hE5 = (unsigned)((ebal << 2) >> lane) & 0x1Fu; \
    hb = (hb << 1) | (hE5 ? 1u : 0u); }

    // ---- pre-roll: rows r0-6, r0-5 ----
    for (int q = 0; q < 2; ++q) { int Lr = r0 - 6 + q; LOADROW(Lr); }
    // ---- warm: rows r0-4..r0-1 (E/hE only) ----
    for (int q = 0; q < 4; ++q) { int Lr = r0 - 4 + q; LOADROW(Lr); SOBEL_E(Lr); }

    // ---- steady: 42 iterations, ring unrolled x7 ----
    float r1p[7], r2p[7], r1v[7], r2v[7];
    unsigned rcn[7];
    unsigned cnt_acc = 0;
    float a1p = 0, a2p = 0, a1v = 0, a2v = 0;
    float c0a = 0, c1a = 0, c2a = 0, c3a = 0;

    for (int o6 = 0; o6 < 6; ++o6) {
#pragma unroll
        for (int u = 0; u < 7; ++u) {
            int j = o6 * 7 + u;
            int Lr = r0 + j;
            LOADROW(Lr);
            SOBEL_E(Lr);
            int m = Lr - 3;
            bool ed = (hb & 0x1Fu) != 0;
            bool e3 = ((eb >> 2) & 1u) != 0;
            bool mrowok = (unsigned)m < HH;
            bool pp = ed && !e3 && mrowok && colok;
            bool vv = (!ed) && mrowok && colok;
            u64 pb = __ballot(pp);
            u64 vb = __ballot(vv);
            pbm = (pbm << 1) | (pp ? 1u : 0u);
            vbm = (vbm << 1) | (vv ? 1u : 0u);

            float xx0 = __shfl(tm0, lm2);   // col-3
            float xx1 = __shfl(tc0, lm2);   // col-2
            float xx2 = tm0;                // col-1
            float xx3 = tc0;                // col
            float xx4 = tp0;                // col+1
            float xx5 = __shfl(tc0, lp2);   // col+2
            float xx6 = __shfl(tp0, lp2);   // col+3
            unsigned pw = (unsigned)((pb << 3) >> lane) & 0x7Fu;
            unsigned vw = (unsigned)((vb << 3) >> lane) & 0x7Fu;
            unsigned cnt_new = (unsigned)__popc(pw) | ((unsigned)__popc(vw) << 8);
            float s1p = 0, s2p = 0, s1v = 0, s2v = 0;
#define TAP(i, xi) { float xq = (xi) * (xi); \
            s1p += ((pw >> (i)) & 1u) ? (xi) : 0.0f; \
            s2p += ((pw >> (i)) & 1u) ? xq : 0.0f; \
            s1v += ((vw >> (i)) & 1u) ? (xi) : 0.0f; \
            s2v += ((vw >> (i)) & 1u) ? xq : 0.0f; }
            TAP(0, xx0) TAP(1, xx1) TAP(2, xx2) TAP(3, xx3)
            TAP(4, xx4) TAP(5, xx5) TAP(6, xx6)
#undef TAP

            if (j >= 7) {   // slide out row m-7
                cnt_acc -= rcn[u];
                a1p -= r1p[u]; a2p -= r2p[u]; a1v -= r1v[u]; a2v -= r2v[u];
            }
            cnt_acc += cnt_new;
            a1p += s1p; a2p += s2p; a1v += s1v; a2v += s2v;
            rcn[u] = cnt_new; r1p[u] = s1p; r2p[u] = s2p; r1v[u] = s1v; r2v[u] = s2v;

            if (j >= 3 && j <= 34) {   // write prox byte for owned row m
                if (lane >= 6 && lane <= 57 && colok)
                    Mo[(size_t)m * WW + col] = (uchar)(pp ? 1 : 0);
            }
            if (j >= 6 && j <= 37) {   // output row y = Lr-6
                float mp0 = (float)((pbm >> 3) & 1u);
                float mb0 = (float)((vbm >> 3) & 1u);
                if (lane < 6 || lane > 57) { mp0 = 0.0f; mb0 = 0.0f; }
                float cpf = (float)(cnt_acc & 0xFFu);
                float cvf = (float)((cnt_acc >> 8) & 0xFFu);
                float rCp = __builtin_amdgcn_rcpf(fmaxf(cpf, 1.0f));
                float meanp = a1p * rCp;
                float varp = fmaxf(a2p * rCp - meanp * meanp, 0.0f);
                float rCb = __builtin_amdgcn_rcpf(fmaxf(cvf, 1.0f));
                float meanb = a1v * rCb;
                float varb = fmaxf(a2v * rCb - meanb * meanb, 0.0f);
                c0a += varp * mp0; c1a += mp0;
                c2a += varb * mb0; c3a += mb0;
            }
        }
    }

    c0a = wave_reduce(c0a); c1a = wave_reduce(c1a);
    c2a = wave_reduce(c2a); c3a = wave_reduce(c3a);
    if (lane == 0) {
        atomicAdd(&acc[img * 4 + 0], (double)c0a);
        atomicAdd(&acc[img * 4 + 1], (double)c1a);
        atomicAdd(&acc[img * 4 + 2], (double)c2a);
        atomicAdd(&acc[img * 4 + 3], (double)c3a);
    }
}

// ---------------- Stage 5a: per-image ringing flags ----------------
__global__ void k_flags(const double* __restrict__ acc, float* __restrict__ flags) {
    int i = threadIdx.x;
    if (i >= NIMG) return;
    const double* a = acc + (size_t)i * 4;
    double vp = a[0] / fmax(a[1], 1.0);
    double vb = a[2] / fmax(a[3], 1.0);
    flags[i] = ((vp / (vb + 1e-12)) > 2.0) ? 1.0f : 0.0f;
}

// ---------------- Stage 5b: output from prox byte masks ----------------
__global__ __launch_bounds__(256) void k_out(const uchar4* __restrict__ M,
                                             const float* __restrict__ flags,
                                             float4* __restrict__ out) {
    int idx = blockIdx.x * 256 + threadIdx.x;   // BATCH * NPIX/4 threads
    int b = idx >> 16;
    int p = idx & 65535;
    float fr = flags[b], ft = flags[b + BATCH];
    uchar4 mr = M[(size_t)b * 65536 + p];
    uchar4 mt = M[(size_t)(b + BATCH) * 65536 + p];
    float4 o;
    o.x = fmaxf((mt.x ? ft : 0.0f) - (mr.x ? fr : 0.0f), 0.0f);
    o.y = fmaxf((mt.y ? ft : 0.0f) - (mr.y ? fr : 0.0f), 0.0f);
    o.z = fmaxf((mt.z ? ft : 0.0f) - (mr.z ? fr : 0.0f), 0.0f);
    o.w = fmaxf((mt.w ? ft : 0.0f) - (mr.w ? fr : 0.0f), 0.0f);
    out[idx] = o;
}

extern "C" void kernel_launch(void* const* d_in, const int* in_sizes, int n_in,
                              void* d_out, int out_size, void* d_ws, size_t ws_size,
                              hipStream_t stream) {
    const float* ref = (const float*)d_in[0];
    const float* tgt = (const float*)d_in[1];
    float* out = (float*)d_out;

    char* ws = (char*)d_ws;
    double* acc = (double*)ws;                       // 32*4 doubles = 1 KB
    float* flags = (float*)(ws + 1024);              // 32 floats
    float* lum = (float*)(ws + 2048);                // 32 MB
    uchar* Mo = (uchar*)(ws + 2048 + (size_t)NIMG * NPIX * 4);  // 8 MB prox bytes

    (void)hipMemsetAsync(acc, 0, NIMG * 4 * sizeof(double), stream);

    int nAll = NIMG * NPIX;          // 8388608
    k_lum<<<nAll / 4 / 256, 256, 0, stream>>>((const float4*)ref, (const float4*)tgt, (float4*)lum);
    k_strip<<<1280, 256, 0, stream>>>(lum, Mo, acc);   // 5120 waves
    k_flags<<<1, 64, 0, stream>>>(acc, flags);
    k_out<<<BATCH * NPIX / 4 / 256, 256, 0, stream>>>((const uchar4*)Mo, flags, (float4*)out);
}